// Round 6
// baseline (207.411 us; speedup 1.0000x reference)
//
#include <hip/hip_runtime.h>
#include <stdint.h>

// ---------------------------------------------------------------------------
// NT-Xent loss, B=8192, D=128, T=0.5, N=16384.
// loss = mean_i( -sim[i,pair(i)] + logsumexp_j sim[i,j] ), diag masked.
//   Sum_i pos_i = 4 * sum(z1 .* z2)                  (exact fp32)
//   lse_i via bf16 MFMA Gram + FIXED-SHIFT exp-sum:
//     zb = bf16(z * sqrt(2*log2e))  =>  mfma y = sim_nat * log2(e)
//     acc initialized to -128  =>  mfma output is y - 128 directly
//     s_i = sum_j exp2(y_ij - 128);  lse_i = ln2 * (128 + log2(s_i))
//   exp2 via RAW v_exp_f32: args < -126 flush to 0 == correct here.
// Round 6: INTRA-WAVE SOFTWARE PIPELINE (T15): exp/accumulate of subtile
// u-1 is interleaved (by the scheduler) into the dependent-MFMA chain of
// subtile u, so the MFMA pipe and VALU/trans pipe run concurrently within
// one wave. Named rotation n -> m -> pA (no runtime indexing, rule #20).
// NQ=8, grid 512 = 2 blocks/CU at the expected ~190-reg occupancy; uniform
// 32 tiles per block. Combine fused into k_main via last-block counter.
// NOTE: plain __launch_bounds__(256) — (512,4) min-waves caused rf spill
// to scratch in round 4 (848MB FETCH). Do not re-add.
// ---------------------------------------------------------------------------

typedef __attribute__((ext_vector_type(8))) short s16x8;     // 8 bf16 (4 VGPR)
typedef __attribute__((ext_vector_type(16))) float f32x16;   // 32x32 mfma acc

#define N_TOT   16384
#define NHALF   8192
#define DDIM    128
#define NQ      8                // column splits (grid 64*8=512 = 2/CU)
#define BN      64               // cols per LDS tile
#define NTILE   32               // tiles per block (uniform: 256/NQ)
#define BM      256              // rows per block (4 waves x 64 rows)
#define NRB     (N_TOT / BM)     // 64 row blocks
#define CSH     128.0f           // fixed exponent shift (log2 units)
#define LN2     0.69314718055994530942f
#define BF_SCALE 1.6986436f      // sqrt(2*log2(e))

__device__ __forceinline__ unsigned short f2bf(float f) {
    union { float f; unsigned int u; } v; v.f = f;
    unsigned int u = v.u;
    unsigned int r = (u + 0x7FFFu + ((u >> 16) & 1u)) >> 16;  // RNE
    return (unsigned short)r;
}

__device__ __forceinline__ void gload_lds16(const void* g, void* l) {
    __builtin_amdgcn_global_load_lds(
        (const __attribute__((address_space(1))) void*)g,
        (__attribute__((address_space(3))) void*)l, 16, 0, 0);
}

// --- fused cast(+scale) + positives partials + counter zeroing --------------
__global__ __launch_bounds__(256) void k_castpos(const float* __restrict__ z1,
                                                 const float* __restrict__ z2,
                                                 unsigned short* __restrict__ zb,
                                                 float* __restrict__ pos_part,
                                                 unsigned int* __restrict__ ctr) {
    __shared__ float red[4];
    int i = blockIdx.x * 256 + threadIdx.x;      // 0..262143
    if (i == 0) ctr[0] = 0u;
    float4 a = ((const float4*)z1)[i];
    float4 b = ((const float4*)z2)[i];
    ushort4 oa, ob;
    oa.x = f2bf(a.x * BF_SCALE); oa.y = f2bf(a.y * BF_SCALE);
    oa.z = f2bf(a.z * BF_SCALE); oa.w = f2bf(a.w * BF_SCALE);
    ob.x = f2bf(b.x * BF_SCALE); ob.y = f2bf(b.y * BF_SCALE);
    ob.z = f2bf(b.z * BF_SCALE); ob.w = f2bf(b.w * BF_SCALE);
    ((ushort4*)zb)[i] = oa;
    ((ushort4*)(zb + (size_t)NHALF * DDIM))[i] = ob;
    float s = a.x * b.x + a.y * b.y + a.z * b.z + a.w * b.w;
    for (int o = 32; o; o >>= 1) s += __shfl_xor(s, o);
    int lane = threadIdx.x & 63, w = threadIdx.x >> 6;
    if (lane == 0) red[w] = s;
    __syncthreads();
    if (threadIdx.x == 0) pos_part[blockIdx.x] = red[0] + red[1] + red[2] + red[3];
}

// --- MFMA one 32-col subtile into (O0,O1) for the wave's two row-sets -------
#define MFMA_SUB(TBASE, SDX, O0, O1) do {                                     \
    const int c_  = (SDX) * 32 + l31;                                         \
    const int cx_ = c_ & 15;                                                  \
    const s16x8* tb_ = (TBASE) + c_ * 16;                                     \
    O0 = acc_init; O1 = acc_init;                                             \
    _Pragma("unroll")                                                         \
    for (int ks_ = 0; ks_ < 8; ++ks_) {                                       \
        s16x8 a_ = tb_[(ks_ * 2 + h) ^ cx_];                                  \
        O0 = __builtin_amdgcn_mfma_f32_32x32x16_bf16(a_, rf0[ks_], O0, 0,0,0);\
        O1 = __builtin_amdgcn_mfma_f32_32x32x16_bf16(a_, rf1[ks_], O1, 0,0,0);\
    } } while (0)

// --- diag-mask + exp-accumulate a finished subtile pair ---------------------
#define EXP_SUB(X0, X1, CB) do {                                              \
    if ((CB) == rowB) {                                                       \
        _Pragma("unroll")                                                     \
        for (int r2_ = 0; r2_ < 16; ++r2_) {                                  \
            int crow_ = (r2_ & 3) + 8 * (r2_ >> 2) + 4 * h;                   \
            if (crow_ == l31) X0[r2_] = -1e30f;                               \
        } }                                                                   \
    if ((CB) == rowB + 32) {                                                  \
        _Pragma("unroll")                                                     \
        for (int r2_ = 0; r2_ < 16; ++r2_) {                                  \
            int crow_ = (r2_ & 3) + 8 * (r2_ >> 2) + 4 * h;                   \
            if (crow_ == l31) X1[r2_] = -1e30f;                               \
        } }                                                                   \
    _Pragma("unroll")                                                         \
    for (int r2_ = 0; r2_ < 16; r2_ += 4) {                                   \
        sa[0] += __builtin_amdgcn_exp2f(X0[r2_ + 0]);                         \
        sa[1] += __builtin_amdgcn_exp2f(X0[r2_ + 1]);                         \
        sa[2] += __builtin_amdgcn_exp2f(X0[r2_ + 2]);                         \
        sa[3] += __builtin_amdgcn_exp2f(X0[r2_ + 3]);                         \
        sb[0] += __builtin_amdgcn_exp2f(X1[r2_ + 0]);                         \
        sb[1] += __builtin_amdgcn_exp2f(X1[r2_ + 1]);                         \
        sb[2] += __builtin_amdgcn_exp2f(X1[r2_ + 2]);                         \
        sb[3] += __builtin_amdgcn_exp2f(X1[r2_ + 3]);                         \
    } } while (0)

// --- main: fused Gram + fixed-shift exp row-sum + fused final combine -------
__global__ __launch_bounds__(256) void k_main(const unsigned short* __restrict__ zb,
                                              float* __restrict__ ps,
                                              const float* __restrict__ pos_part,
                                              unsigned int* __restrict__ ctr,
                                              float* __restrict__ out) {
    __shared__ s16x8 tile[3][BN * 16];   // 3 x 16KB

    const int tid  = threadIdx.x;
    const int lane = tid & 63;
    const int w    = tid >> 6;           // 0..3
    const int h    = lane >> 5;
    const int l31  = lane & 31;

    const int bid = blockIdx.x;
    const int q   = bid >> 6;            // 0..NQ-1
    const int rb  = bid & 63;            // row block
    const int rowB   = rb * BM + w * 64;
    const int tstart = q * NTILE;

    // row fragments for two 32-row sets (mfma B operand)
    s16x8 rf0[8], rf1[8];
    {
        const s16x8* rp0 = (const s16x8*)(zb + (size_t)(rowB + l31) * DDIM);
        const s16x8* rp1 = (const s16x8*)(zb + (size_t)(rowB + 32 + l31) * DDIM);
        #pragma unroll
        for (int ks = 0; ks < 8; ++ks) { rf0[ks] = rp0[ks * 2 + h]; rf1[ks] = rp1[ks * 2 + h]; }
    }

    // staging: 16 wave-issues/tile (4 per wave); inverse-swizzled global src
    int soff[4];
    #pragma unroll
    for (int j = 0; j < 4; ++j) {
        int e = w * 4 + j;
        int col = e * 4 + (lane >> 4);
        int chunk = (lane & 15) ^ (col & 15);
        soff[j] = col * 256 + chunk * 16;
    }

    // prologue: issue tiles 0 and 1 (8 outstanding loads per wave)
    #pragma unroll
    for (int j = 0; j < 4; ++j)
        gload_lds16((const char*)zb + (size_t)tstart * 16384 + soff[j],
                    (char*)(&tile[0][0]) + (w * 4 + j) * 1024);
    #pragma unroll
    for (int j = 0; j < 4; ++j)
        gload_lds16((const char*)zb + (size_t)(tstart + 1) * 16384 + soff[j],
                    (char*)(&tile[1][0]) + (w * 4 + j) * 1024);

    const f32x16 acc_init = {-CSH, -CSH, -CSH, -CSH, -CSH, -CSH, -CSH, -CSH,
                             -CSH, -CSH, -CSH, -CSH, -CSH, -CSH, -CSH, -CSH};
    float sa[4] = {0.f, 0.f, 0.f, 0.f};
    float sb[4] = {0.f, 0.f, 0.f, 0.f};
    f32x16 pA0, pA1, n0, n1, m0, m1;
    int pcb;

    // ---- peel tile 0 (fills the pipeline: leaves (0,1) in pA) ----
    asm volatile("s_waitcnt vmcnt(4)" ::: "memory");
    __builtin_amdgcn_s_barrier();
    #pragma unroll
    for (int j = 0; j < 4; ++j)          // prefetch tile 2 into buf 2
        gload_lds16((const char*)zb + (size_t)(tstart + 2) * 16384 + soff[j],
                    (char*)(&tile[0][0]) + 2 * 16384 + (w * 4 + j) * 1024);
    {
        const s16x8* tbase = &tile[0][0];
        MFMA_SUB(tbase, 0, n0, n1);
        MFMA_SUB(tbase, 1, pA0, pA1);
        EXP_SUB(n0, n1, tstart * BN);
        pcb = tstart * BN + 32;
    }

    int bc = 1, bp = 0;
    for (int t = 1; t < NTILE; ++t) {
        if (t < NTILE - 1) asm volatile("s_waitcnt vmcnt(4)" ::: "memory");
        else               asm volatile("s_waitcnt vmcnt(0)" ::: "memory");
        __builtin_amdgcn_s_barrier();
        if (t + 2 < NTILE) {             // refill freed buffer with tile t+2
            #pragma unroll
            for (int j = 0; j < 4; ++j)
                gload_lds16((const char*)zb + (size_t)(tstart + t + 2) * 16384 + soff[j],
                            (char*)(&tile[0][0]) + bp * 16384 + (w * 4 + j) * 1024);
        }
        const s16x8* tbase = &tile[0][0] + bc * (BN * 16);
        const int cb0 = (tstart + t) * BN;
        // pipeline: exps of finished subtiles interleave into MFMA dep-gaps
        MFMA_SUB(tbase, 0, n0, n1);
        EXP_SUB(pA0, pA1, pcb);          // prev tile's sdx=1
        MFMA_SUB(tbase, 1, m0, m1);
        EXP_SUB(n0, n1, cb0);            // this tile's sdx=0
        pA0 = m0; pA1 = m1; pcb = cb0 + 32;
        bc = (bc == 2) ? 0 : bc + 1;
        bp = (bp == 2) ? 0 : bp + 1;
    }
    EXP_SUB(pA0, pA1, pcb);              // drain last subtile

    // merge the two col-half lanes (l, l+32) of each row; write partials
    float sA = (sa[0] + sa[1]) + (sa[2] + sa[3]);
    float sB = (sb[0] + sb[1]) + (sb[2] + sb[3]);
    sA += __shfl_xor(sA, 32);
    sB += __shfl_xor(sB, 32);
    if (lane < 32) {
        ps[(size_t)q * N_TOT + rowB + l31]      = sA;
        ps[(size_t)q * N_TOT + rowB + 32 + l31] = sB;
    }

    // ---- fused combine: last block to finish reduces everything ----
    __shared__ float red[4];
    __shared__ int lastFlag;
    __threadfence();
    __syncthreads();
    if (tid == 0) {
        unsigned int old = atomicAdd(ctr, 1u);
        lastFlag = (old == (unsigned)(NRB * NQ - 1)) ? 1 : 0;
    }
    __syncthreads();
    if (!lastFlag) return;
    __threadfence();                     // acquire all blocks' ps writes

    float ls = 0.f;
    for (int row = tid; row < N_TOT; row += 256) {
        float s = 0.f;
        #pragma unroll
        for (int qq = 0; qq < NQ; ++qq) s += ps[(size_t)qq * N_TOT + row];
        ls += CSH + __builtin_amdgcn_logf(s);   // log2 units
    }
    for (int o = 32; o; o >>= 1) ls += __shfl_xor(ls, o);
    if (lane == 0) red[w] = ls;
    __syncthreads();
    float p = pos_part[tid] + pos_part[tid + 256] +
              pos_part[tid + 512] + pos_part[tid + 768];
    for (int o = 32; o; o >>= 1) p += __shfl_xor(p, o);
    __shared__ float redp[4];
    if (lane == 0) redp[w] = p;
    __syncthreads();
    if (tid == 0) {
        float lse_tot = LN2 * (red[0] + red[1] + red[2] + red[3]);
        float pos_tot = redp[0] + redp[1] + redp[2] + redp[3];
        out[0] = (lse_tot - 4.0f * pos_tot) * (1.0f / (float)N_TOT);
    }
}

extern "C" void kernel_launch(void* const* d_in, const int* in_sizes, int n_in,
                              void* d_out, int out_size, void* d_ws, size_t ws_size,
                              hipStream_t stream) {
    const float* z1 = (const float*)d_in[0];
    const float* z2 = (const float*)d_in[1];
    float* out = (float*)d_out;

    char* ws = (char*)d_ws;
    float* ps          = (float*)ws;                         // NQ*N floats (512KB)
    unsigned int* ctr  = (unsigned int*)(ws + (1u << 20));   // 1 uint
    float* pos_part    = (float*)(ws + (1u << 20) + 1024);   // 1024 floats
    unsigned short* zb = (unsigned short*)(ws + (2u << 20)); // 4 MB bf16

    k_castpos<<<dim3(1024), dim3(256), 0, stream>>>(z1, z2, zb, pos_part, ctr);
    k_main<<<dim3(NRB * NQ), dim3(256), 0, stream>>>(zb, ps, pos_part, ctr, out);
}

// Round 7
// 134.920 us; speedup vs baseline: 1.5373x; 1.5373x over previous
//
#include <hip/hip_runtime.h>
#include <stdint.h>

// ---------------------------------------------------------------------------
// NT-Xent loss, B=8192, D=128, T=0.5, N=16384.
// loss = mean_i( -sim[i,pair(i)] + logsumexp_j sim[i,j] ), diag masked.
//   Sum_i pos_i = 4 * sum(z1 .* z2)                  (exact fp32)
//   lse_i via bf16 MFMA Gram + FIXED-SHIFT exp-sum:
//     zb = bf16(z * sqrt(2*log2e))  =>  mfma y = sim_nat * log2(e)
//     acc initialized to -128  =>  mfma output is y - 128 directly
//     s_i = sum_j exp2(y_ij - 128);  lse_i = ln2 * (128 + log2(s_i))
//   exp2 via RAW v_exp_f32: args < -126 flush to 0 == correct here.
// Round 7: round-3 skeleton (NQ=16, grid 1024, 2-buffer LDS, vmcnt(4) +
// 2 barriers/tile — proven 84 us) + ONE change: intra-wave A/B acc
// alternation so the exp block of the finished subtile interleaves into
// the current subtile's dependent-MFMA chain (MFMA pipe || trans pipe).
// NOTE: plain __launch_bounds__(256) — (512,4) min-waves caused rf spill
// to scratch in round 4 (848MB FETCH). Do not re-add.
// ---------------------------------------------------------------------------

typedef __attribute__((ext_vector_type(8))) short s16x8;     // 8 bf16 (4 VGPR)
typedef __attribute__((ext_vector_type(16))) float f32x16;   // 32x32 mfma acc

#define N_TOT   16384
#define NHALF   8192
#define DDIM    128
#define NQ      16               // column splits (grid 64*16=1024)
#define QW      (N_TOT / NQ)     // 1024 cols per block
#define BN      64               // cols per LDS tile
#define NT      (QW / BN)        // 16 tiles per block
#define BM      256              // rows per block (4 waves x 64 rows)
#define NRB     (N_TOT / BM)     // 64 row blocks
#define CSH     128.0f           // fixed exponent shift (log2 units)
#define LN2     0.69314718055994530942f
#define BF_SCALE 1.6986436f      // sqrt(2*log2(e))

__device__ __forceinline__ unsigned short f2bf(float f) {
    union { float f; unsigned int u; } v; v.f = f;
    unsigned int u = v.u;
    unsigned int r = (u + 0x7FFFu + ((u >> 16) & 1u)) >> 16;  // RNE
    return (unsigned short)r;
}

__device__ __forceinline__ void gload_lds16(const void* g, void* l) {
    __builtin_amdgcn_global_load_lds(
        (const __attribute__((address_space(1))) void*)g,
        (__attribute__((address_space(3))) void*)l, 16, 0, 0);
}

// --- fused cast(+scale) + positives partials + ws accumulator zeroing -------
__global__ __launch_bounds__(256) void k_castpos(const float* __restrict__ z1,
                                                 const float* __restrict__ z2,
                                                 unsigned short* __restrict__ zb,
                                                 float* __restrict__ pos_part,
                                                 float* __restrict__ ws_acc) {
    __shared__ float red[4];
    int i = blockIdx.x * 256 + threadIdx.x;      // 0..262143
    if (i == 0) { ws_acc[0] = 0.f; ((unsigned int*)ws_acc)[1] = 0u; }
    float4 a = ((const float4*)z1)[i];
    float4 b = ((const float4*)z2)[i];
    ushort4 oa, ob;
    oa.x = f2bf(a.x * BF_SCALE); oa.y = f2bf(a.y * BF_SCALE);
    oa.z = f2bf(a.z * BF_SCALE); oa.w = f2bf(a.w * BF_SCALE);
    ob.x = f2bf(b.x * BF_SCALE); ob.y = f2bf(b.y * BF_SCALE);
    ob.z = f2bf(b.z * BF_SCALE); ob.w = f2bf(b.w * BF_SCALE);
    ((ushort4*)zb)[i] = oa;
    ((ushort4*)(zb + (size_t)NHALF * DDIM))[i] = ob;
    float s = a.x * b.x + a.y * b.y + a.z * b.z + a.w * b.w;
    for (int o = 32; o; o >>= 1) s += __shfl_xor(s, o);
    int lane = threadIdx.x & 63, w = threadIdx.x >> 6;
    if (lane == 0) red[w] = s;
    __syncthreads();
    if (threadIdx.x == 0) pos_part[blockIdx.x] = red[0] + red[1] + red[2] + red[3];
}

// --- MFMA one 32-col subtile into (O0,O1) for the wave's two row-sets -------
#define MFMA_SUB(TBASE, SDX, O0, O1) do {                                     \
    const int c_  = (SDX) * 32 + l31;                                         \
    const int cx_ = c_ & 15;                                                  \
    const s16x8* tb_ = (TBASE) + c_ * 16;                                     \
    O0 = acc_init; O1 = acc_init;                                             \
    _Pragma("unroll")                                                         \
    for (int ks_ = 0; ks_ < 8; ++ks_) {                                       \
        s16x8 a_ = tb_[(ks_ * 2 + h) ^ cx_];                                  \
        O0 = __builtin_amdgcn_mfma_f32_32x32x16_bf16(a_, rf0[ks_], O0, 0,0,0);\
        O1 = __builtin_amdgcn_mfma_f32_32x32x16_bf16(a_, rf1[ks_], O1, 0,0,0);\
    } } while (0)

// --- diag-mask + exp-accumulate a finished subtile pair ---------------------
#define EXP_SUB(X0, X1, CB) do {                                              \
    if ((CB) == rowB) {                                                       \
        _Pragma("unroll")                                                     \
        for (int r2_ = 0; r2_ < 16; ++r2_) {                                  \
            int crow_ = (r2_ & 3) + 8 * (r2_ >> 2) + 4 * h;                   \
            if (crow_ == l31) X0[r2_] = -1e30f;                               \
        } }                                                                   \
    if ((CB) == rowB + 32) {                                                  \
        _Pragma("unroll")                                                     \
        for (int r2_ = 0; r2_ < 16; ++r2_) {                                  \
            int crow_ = (r2_ & 3) + 8 * (r2_ >> 2) + 4 * h;                   \
            if (crow_ == l31) X1[r2_] = -1e30f;                               \
        } }                                                                   \
    _Pragma("unroll")                                                         \
    for (int r2_ = 0; r2_ < 16; r2_ += 4) {                                   \
        sa[0] += __builtin_amdgcn_exp2f(X0[r2_ + 0]);                         \
        sa[1] += __builtin_amdgcn_exp2f(X0[r2_ + 1]);                         \
        sa[2] += __builtin_amdgcn_exp2f(X0[r2_ + 2]);                         \
        sa[3] += __builtin_amdgcn_exp2f(X0[r2_ + 3]);                         \
        sb[0] += __builtin_amdgcn_exp2f(X1[r2_ + 0]);                         \
        sb[1] += __builtin_amdgcn_exp2f(X1[r2_ + 1]);                         \
        sb[2] += __builtin_amdgcn_exp2f(X1[r2_ + 2]);                         \
        sb[3] += __builtin_amdgcn_exp2f(X1[r2_ + 3]);                         \
    } } while (0)

// --- main: fused Gram + fixed-shift exp row-sum -----------------------------
__global__ __launch_bounds__(256) void k_main(const unsigned short* __restrict__ zb,
                                              float* __restrict__ ps) {
    __shared__ s16x8 tile[2][BN * 16];   // 2 x 16KB

    const int tid  = threadIdx.x;
    const int lane = tid & 63;
    const int w    = tid >> 6;           // 0..3
    const int h    = lane >> 5;
    const int l31  = lane & 31;

    const int bid = blockIdx.x;
    const int q   = bid >> 6;            // 0..NQ-1
    const int rb  = bid & 63;            // row block
    const int rowB     = rb * BM + w * 64;
    const int colStart = q * QW;

    // row fragments for two 32-row sets (mfma B operand)
    s16x8 rf0[8], rf1[8];
    {
        const s16x8* rp0 = (const s16x8*)(zb + (size_t)(rowB + l31) * DDIM);
        const s16x8* rp1 = (const s16x8*)(zb + (size_t)(rowB + 32 + l31) * DDIM);
        #pragma unroll
        for (int ks = 0; ks < 8; ++ks) { rf0[ks] = rp0[ks * 2 + h]; rf1[ks] = rp1[ks * 2 + h]; }
    }

    // staging: 16 wave-issues/tile (4 per wave). Issue e, lane l writes linear
    // LDS chunk e*64+l; inverse-swizzled global source col=e*4+(l>>4),
    // chunk=(l&15)^(col&15)  ==> LDS holds swizzled layout.
    int soff[4];
    #pragma unroll
    for (int j = 0; j < 4; ++j) {
        int e = w * 4 + j;
        int col = e * 4 + (lane >> 4);
        int chunk = (lane & 15) ^ (col & 15);
        soff[j] = col * 256 + chunk * 16;          // bytes within tile span
    }

    // prologue: issue tiles 0 and 1 (8 outstanding loads per wave)
    #pragma unroll
    for (int j = 0; j < 4; ++j)
        gload_lds16((const char*)zb + (size_t)colStart * 256 + soff[j],
                    (char*)(&tile[0][0]) + (w * 4 + j) * 1024);
    #pragma unroll
    for (int j = 0; j < 4; ++j)
        gload_lds16((const char*)zb + (size_t)(colStart + BN) * 256 + soff[j],
                    (char*)(&tile[1][0]) + (w * 4 + j) * 1024);

    const f32x16 acc_init = {-CSH, -CSH, -CSH, -CSH, -CSH, -CSH, -CSH, -CSH,
                             -CSH, -CSH, -CSH, -CSH, -CSH, -CSH, -CSH, -CSH};
    float sa[4] = {0.f, 0.f, 0.f, 0.f};
    float sb[4] = {0.f, 0.f, 0.f, 0.f};
    f32x16 A0, A1, B0, B1;               // two alternating acc pairs
    int pcb;                             // col-base of the pair waiting in B

    // ---- peel tile 0 (establishes invariant: B holds prev subtile) ----
    asm volatile("s_waitcnt vmcnt(4)" ::: "memory");
    __builtin_amdgcn_s_barrier();
    {
        const s16x8* tbase = &tile[0][0];
        MFMA_SUB(tbase, 0, A0, A1);
        MFMA_SUB(tbase, 1, B0, B1);
        EXP_SUB(A0, A1, colStart);
        pcb = colStart + 32;
    }
    __builtin_amdgcn_s_barrier();        // all waves done reading buf 0
    #pragma unroll
    for (int j = 0; j < 4; ++j)          // refill buf 0 with tile 2
        gload_lds16((const char*)zb + (size_t)(colStart + 2 * BN) * 256 + soff[j],
                    (char*)(&tile[0][0]) + (w * 4 + j) * 1024);

    for (int t = 1; t < NT; ++t) {
        // gate: tile t's 4 loads done; tile t+1's 4 stay in flight
        if (t < NT - 1) asm volatile("s_waitcnt vmcnt(4)" ::: "memory");
        else            asm volatile("s_waitcnt vmcnt(0)" ::: "memory");
        __builtin_amdgcn_s_barrier();    // tile t visible to all waves
        const s16x8* tbase = &tile[0][0] + (t & 1) * (BN * 16);
        const int cb0 = colStart + t * BN;
        // interleave: exp of finished pair sits inside current MFMA chain
        MFMA_SUB(tbase, 0, A0, A1);
        EXP_SUB(B0, B1, pcb);            // prev tile's sdx=1 (trans || MFMA)
        MFMA_SUB(tbase, 1, B0, B1);
        EXP_SUB(A0, A1, cb0);            // this tile's sdx=0 (trans || MFMA)
        pcb = cb0 + 32;
        __builtin_amdgcn_s_barrier();    // all waves done reading this buf
        if (t + 2 < NT) {                // refill freed buffer with tile t+2
            #pragma unroll
            for (int j = 0; j < 4; ++j)
                gload_lds16((const char*)zb + (size_t)(colStart + (t + 2) * BN) * 256 + soff[j],
                            (char*)(&tile[0][0]) + (t & 1) * 16384 + (w * 4 + j) * 1024);
        }
    }
    EXP_SUB(B0, B1, pcb);                // drain last subtile

    // merge the two col-half lanes (l, l+32) of each row; write partials
    float sA = (sa[0] + sa[1]) + (sa[2] + sa[3]);
    float sB = (sb[0] + sb[1]) + (sb[2] + sb[3]);
    sA += __shfl_xor(sA, 32);
    sB += __shfl_xor(sB, 32);
    if (lane < 32) {
        ps[(size_t)q * N_TOT + rowB + l31]      = sA;
        ps[(size_t)q * N_TOT + rowB + 32 + l31] = sB;
    }
}

// --- combine NQ partials -> lse, grid-reduce, last block writes out ---------
__global__ __launch_bounds__(256) void k_cf(const float* __restrict__ ps,
                                            const float* __restrict__ pos_part,
                                            float* __restrict__ ws_acc,
                                            float* __restrict__ out) {
    __shared__ float red[4];
    __shared__ int last;
    const int tid = threadIdx.x;
    const int base = blockIdx.x * 1024;
    float ls = 0.f;
    #pragma unroll
    for (int k = 0; k < 4; ++k) {
        int row = base + k * 256 + tid;
        float s = 0.f;
        #pragma unroll
        for (int qq = 0; qq < NQ; ++qq) s += ps[(size_t)qq * N_TOT + row];
        ls += LN2 * (CSH + log2f(s));
    }
    for (int o = 32; o; o >>= 1) ls += __shfl_xor(ls, o);
    int lane = tid & 63, wv = tid >> 6;
    if (lane == 0) red[wv] = ls;
    __syncthreads();
    if (tid == 0) {
        atomicAdd(&ws_acc[0], red[0] + red[1] + red[2] + red[3]);
        __threadfence();
        unsigned int old = atomicAdd(&((unsigned int*)ws_acc)[1], 1u);
        last = (old == 15u) ? 1 : 0;
    }
    __syncthreads();
    if (last) {
        float p = pos_part[tid] + pos_part[tid + 256] +
                  pos_part[tid + 512] + pos_part[tid + 768];
        for (int o = 32; o; o >>= 1) p += __shfl_xor(p, o);
        if (lane == 0) red[wv] = p;
        __syncthreads();
        if (tid == 0) {
            float lse_tot = atomicAdd(&ws_acc[0], 0.f);   // coherent read
            float pos_tot = red[0] + red[1] + red[2] + red[3];
            out[0] = (lse_tot - 4.0f * pos_tot) * (1.0f / (float)N_TOT);
        }
    }
}

extern "C" void kernel_launch(void* const* d_in, const int* in_sizes, int n_in,
                              void* d_out, int out_size, void* d_ws, size_t ws_size,
                              hipStream_t stream) {
    const float* z1 = (const float*)d_in[0];
    const float* z2 = (const float*)d_in[1];
    float* out = (float*)d_out;

    char* ws = (char*)d_ws;
    float* ps       = (float*)ws;                          // NQ*N floats = 1 MB
    float* ws_acc   = (float*)(ws + (1u << 20));           // [lse_acc, ctr]
    float* pos_part = (float*)(ws + (1u << 20) + 1024);    // 1024 floats
    unsigned short* zb = (unsigned short*)(ws + (2u << 20)); // 4 MB bf16

    k_castpos<<<dim3(1024), dim3(256), 0, stream>>>(z1, z2, zb, pos_part, ws_acc);
    k_main<<<dim3(NRB * NQ), dim3(256), 0, stream>>>(zb, ps);
    k_cf<<<dim3(16), dim3(256), 0, stream>>>(ps, pos_part, ws_acc, out);
}